// Round 1
// baseline (185.477 us; speedup 1.0000x reference)
//
#include <hip/hip_runtime.h>
#include <math.h>

// DiffAttn flash R11 — R10 body with: (a) double-buffered K/V staging and ONE
// barrier per round (was 2): round = QK -> commit next tile to alt buffer ->
// global prefetch r+2 -> softmax -> PV -> barrier. (b) softmax VALU diet:
// log2e folded into Q prescale (bare v_exp_f32), packed f16 convert via
// v_cvt_pkrtz, row-sum via v_dot2_f32_f16. (c) prep_k/prep_v/lambda merged
// into one dispatch. LDS 64KB (grid caps at 2 blk/CU anyway).
// B=2, 8 head-pairs, T=S=2048, D=64, DV=128, fp32 in/out.

#define NT    2048
#define D     64
#define DV    128
#define TQ    64
#define TS    32
#define NROUND (NT / (2 * TS))   // 32 rounds, 2 tiles/round (one per ks group)

#define LAMBDA_INIT 0.70082066706704814f   // 0.8 - 0.6*exp(-1.8)
#define OUT_SCALE   0.29917933293295186f   // 1 - LAMBDA_INIT
#define QSCALE      0.18033688011112042f   // 0.125 * log2(e): softmax in exp2 domain

typedef __attribute__((ext_vector_type(8)))  short    short8;
typedef __attribute__((ext_vector_type(4)))  short    short4v;
typedef __attribute__((ext_vector_type(8)))  _Float16 half8;
typedef __attribute__((ext_vector_type(2)))  __fp16   fp16x2;
typedef __attribute__((ext_vector_type(4)))  float    f32x4;
typedef unsigned short u16;
typedef unsigned int   u32;

#define MFMAH(a, b, c)  __builtin_amdgcn_mfma_f32_16x16x32_f16(a, b, c, 0, 0, 0)
#define MFMA16(a, b, c) __builtin_amdgcn_mfma_f32_16x16x32_bf16(a, b, c, 0, 0, 0)

#if __has_builtin(__builtin_amdgcn_exp2f)
#define EXP2F(x) __builtin_amdgcn_exp2f(x)
#else
#define EXP2F(x) exp2f(x)
#endif

union Hu { half8 v; _Float16 e[8]; u16 s[8]; short8 sv; };

__device__ __forceinline__ u16 f2h(float x) {
    Hu u; u.e[0] = (_Float16)x; return u.s[0];
}

// ---------------- prep_kv: one dispatch for K-convert + lambda + V-transform
// blocks 0..2047: K f32 -> fp16.  block 2048: lambda.  blocks 2049..2560:
// V -> fp16 transposed [e][s'] with baked 16x16 kappa permutation: within each
// 32-key group, chunk c (c=0..3) slot j holds key 4c + (j&3) + 16*(j>>2).
__global__ __launch_bounds__(256) void prep_kv(
    const float* __restrict__ Kg, const float* __restrict__ Vg,
    const float* __restrict__ lq1, const float* __restrict__ lk1,
    const float* __restrict__ lq2, const float* __restrict__ lk2,
    u16* __restrict__ Kf, u16* __restrict__ Vf, float* __restrict__ lamw)
{
    __shared__ u16 th[64 * 136];   // [e][s] tile, stride 136 (V path only)
    const int bid = blockIdx.x;
    const int t   = threadIdx.x;
    if (bid < 2048) {
        const int idx = (bid * 256 + t) * 8;
        const float4 a = *(const float4*)(Kg + idx);
        const float4 b = *(const float4*)(Kg + idx + 4);
        Hu H;
        H.e[0] = (_Float16)a.x; H.e[1] = (_Float16)a.y;
        H.e[2] = (_Float16)a.z; H.e[3] = (_Float16)a.w;
        H.e[4] = (_Float16)b.x; H.e[5] = (_Float16)b.y;
        H.e[6] = (_Float16)b.z; H.e[7] = (_Float16)b.w;
        *(short8*)(Kf + idx) = H.sv;
        return;
    }
    if (bid == 2048) {
        if (t == 0) {
            float t1 = 0.f, t2 = 0.f;
            for (int i = 0; i < D; ++i) {
                t1 = fmaf(lq1[i], lk1[i], t1);
                t2 = fmaf(lq2[i], lk2[i], t2);
            }
            lamw[0] = __expf(t1) - __expf(t2) + LAMBDA_INIT;
        }
        return;
    }
    const int i  = bid - 2049;
    const int bh = i >> 5;
    const int eb = (i >> 4) & 1;
    const int sb = i & 15;
    const size_t vbase = (size_t)bh * NT * DV + (size_t)sb * 128 * DV + eb * 64;
    {
        const int r0 = t >> 4;
        const int c4 = (t & 15) * 4;
        #pragma unroll
        for (int rr = 0; rr < 8; ++rr) {
            const int row = r0 + rr * 16;
            const float4 x = *(const float4*)(Vg + vbase + (size_t)row * DV + c4);
            th[(c4 + 0) * 136 + row] = f2h(x.x);
            th[(c4 + 1) * 136 + row] = f2h(x.y);
            th[(c4 + 2) * 136 + row] = f2h(x.z);
            th[(c4 + 3) * 136 + row] = f2h(x.w);
        }
    }
    __syncthreads();
    const int e  = t >> 2;
    const int g  = t & 3;          // 32-key group 0..3 (of the 128-s block)
    const size_t orow = ((size_t)bh * DV + eb * 64 + e) * NT + sb * 128;
    #pragma unroll
    for (int c = 0; c < 4; ++c) {  // storage chunk within group
        Hu o;
        #pragma unroll
        for (int j = 0; j < 8; ++j)
            o.s[j] = th[e * 136 + g * 32 + 4 * c + (j & 3) + 16 * (j >> 2)];
        *(short8*)(Vf + orow + g * 32 + c * 8) = o.sv;   // 64B contig/thread
    }
}

// --------------------------------- flash kernel ------------------------------
// LDS: two 32KB staging buffers (double-buffered by round parity).
// Within a buffer, 16B chunks: K group ks: [ks*512 + hh*256 + n*8 + (db ^ (n&7))]
//                              V group ks: [1024 + ks*512 + e*4 + (u ^ ((e>>1)&3))]
struct SmemF {
    union {
        short8 c[4096];                    // 65536 B (2 x 32KB round buffers)
        struct {
            float epi[2][32][132];         // 33792 B
            float lbuf[2][2][2][32];       //  1024 B  [hh][ks][stripe][row]
        } e;
    };
};

__global__ __launch_bounds__(512, 4) void diffattn_mfma11(
    const float* __restrict__ Qg,
    const u16* __restrict__ Kf, const u16* __restrict__ Vf,
    const float* __restrict__ lamw,
    const float* __restrict__ Wg, float* __restrict__ Outg)
{
    __shared__ SmemF sm;

    const int tid    = threadIdx.x;
    const int wv     = tid >> 6;
    const int lane   = tid & 63;
    const int quad   = lane >> 4;
    const int lc     = lane & 15;
    const int stripe = wv & 1;          // 32-row half of the 64-row q-tile
    const int hh     = (wv >> 1) & 1;   // half-head (softmax 1 vs 2)
    const int ks     = wv >> 2;         // key-split group: tiles 2r+ks
    const int wig    = wv & 3;          // wave index within ks group
    const int qt     = blockIdx.x;
    const int bh     = blockIdx.y;
    const int b      = bh >> 3, h = bh & 7;

    const int head2b = b * 16 + 2 * h;
    const int bh8    = b * 8 + h;
    const float lam  = lamw[0];

    // Q B-frags (B[k=d][n=qrow]: n=lc, k=quad*8+j within k0*32), pre-scaled by
    // 0.125*log2e so softmax is a bare v_exp_f32 in exp2 domain.
    half8 qf[2][2];
    {
        const size_t qhead = (size_t)(head2b + hh) * NT * D;
        #pragma unroll
        for (int nq = 0; nq < 2; ++nq) {
            const int row = qt * TQ + stripe * 32 + nq * 16 + lc;
            #pragma unroll
            for (int k0 = 0; k0 < 2; ++k0) {
                const int d0 = k0 * 32 + quad * 8;
                const float4 x = *(const float4*)(Qg + qhead + (size_t)row * D + d0);
                const float4 y = *(const float4*)(Qg + qhead + (size_t)row * D + d0 + 4);
                Hu q;
                q.e[0] = (_Float16)(x.x * QSCALE); q.e[1] = (_Float16)(x.y * QSCALE);
                q.e[2] = (_Float16)(x.z * QSCALE); q.e[3] = (_Float16)(x.w * QSCALE);
                q.e[4] = (_Float16)(y.x * QSCALE); q.e[5] = (_Float16)(y.y * QSCALE);
                q.e[6] = (_Float16)(y.z * QSCALE); q.e[7] = (_Float16)(y.w * QSCALE);
                qf[nq][k0] = q.v;
            }
        }
    }

    f32x4 O_[2][8];   // [nq][nt]: row = nq*16+quad*4+i, e = nt*16+lc
    #pragma unroll
    for (int nq = 0; nq < 2; ++nq)
        #pragma unroll
        for (int nt = 0; nt < 8; ++nt) O_[nq][nt] = (f32x4){0.f, 0.f, 0.f, 0.f};
    float lac[2] = {0.f, 0.f};

    // staging roles: group stages its own 8KB K + 8KB V per round;
    // lane handles 2 consecutive 16B chunks of each (32B contig global).
    u32 gK[2], gV[2];
    int kDst[2], vDst[2];
    #pragma unroll
    for (int j = 0; j < 2; ++j) {
        const int ck  = wig * 128 + lane * 2 + j;     // K chunk 0..511
        const int hhs = ck >> 8;
        const int n   = (ck >> 3) & 31;
        const int db  = ck & 7;
        gK[j]   = (u32)(((head2b + hhs) * NT + n) * D + db * 8);
        kDst[j] = ks * 512 + hhs * 256 + n * 8 + (db ^ (n & 7));
        const int cv = wig * 128 + lane * 2 + j;      // V chunk 0..511
        const int e  = cv >> 2;
        const int u  = cv & 3;
        gV[j]   = (u32)((bh8 * DV + e) * NT + u * 8);
        vDst[j] = 1024 + ks * 512 + e * 4 + (u ^ ((e >> 1) & 3));
    }

    // frag LDS offsets (u16 units, within one round buffer)
    u32 kOff[2][2];
    #pragma unroll
    for (int k0 = 0; k0 < 2; ++k0)
        #pragma unroll
        for (int mt = 0; mt < 2; ++mt)
            kOff[k0][mt] = (u32)((ks * 512 + hh * 256 + (mt * 16 + lc) * 8 +
                                  ((4 * k0 + quad) ^ (lc & 7))) * 8);
    u32 vOff[8];
    {
        const int swzv = quad ^ ((lc >> 1) & 3);
        #pragma unroll
        for (int nt = 0; nt < 8; ++nt)
            vOff[nt] = (u32)((1024 + ks * 512 + (nt * 16 + lc) * 4 + swzv) * 8);
    }

    const u16* ldsu = (const u16*)&sm.c[0];

    // prologue: load tile ks, commit to buffer 0, prefetch tile 2+ks to regs
    short8 pk[2], pv[2];
    #pragma unroll
    for (int j = 0; j < 2; ++j) {
        pk[j] = *(const short8*)(Kf + gK[j] + (u32)ks * (TS * D));
        pv[j] = *(const short8*)(Vf + gV[j] + (u32)ks * TS);
    }
    sm.c[kDst[0]] = pk[0];
    sm.c[kDst[1]] = pk[1];
    sm.c[vDst[0]] = pv[0];
    sm.c[vDst[1]] = pv[1];
    {
        const u32 tn = (u32)(2 + ks);
        #pragma unroll
        for (int j = 0; j < 2; ++j) {
            pk[j] = *(const short8*)(Kf + gK[j] + tn * (TS * D));
            pv[j] = *(const short8*)(Vf + gV[j] + tn * TS);
        }
    }
    __syncthreads();

    const fp16x2 ones = {(__fp16)1.f, (__fp16)1.f};

    for (int r = 0; r < NROUND; ++r) {
        const u32 bo = ((u32)(r & 1)) << 14;        // current buffer, u16 units

        // ---- S^T = K·Q^T: key = mt*16 + quad*4 + i, qrow = nq*16 + lc
        f32x4 sf[2][2];
        #pragma unroll
        for (int mt = 0; mt < 2; ++mt)
            #pragma unroll
            for (int nq = 0; nq < 2; ++nq) sf[mt][nq] = (f32x4){0.f, 0.f, 0.f, 0.f};
        #pragma unroll
        for (int k0 = 0; k0 < 2; ++k0) {
            #pragma unroll
            for (int mt = 0; mt < 2; ++mt) {
                const half8 kfr = *(const half8*)(ldsu + bo + kOff[k0][mt]);
                #pragma unroll
                for (int nq = 0; nq < 2; ++nq)
                    sf[mt][nq] = MFMAH(kfr, qf[nq][k0], sf[mt][nq]);
            }
        }

        // ---- commit tile r+1 into the ALTERNATE buffer (peers finished
        // reading it in round r-1; they read it next after this round's
        // barrier). No second barrier needed.
        if (r < NROUND - 1) {
            const int cd = ((r & 1) ^ 1) << 11;     // 2048 chunks = 32KB
            sm.c[cd + kDst[0]] = pk[0];
            sm.c[cd + kDst[1]] = pk[1];
            sm.c[cd + vDst[0]] = pv[0];
            sm.c[cd + vDst[1]] = pv[1];
        }
        // ---- prefetch tile r+2 — in flight across the rest of the round +
        // the whole next round.
        if (r < NROUND - 2) {
            const u32 tn = (u32)(2 * (r + 2) + ks);
            #pragma unroll
            for (int j = 0; j < 2; ++j) {
                pk[j] = *(const short8*)(Kf + gK[j] + tn * (TS * D));
                pv[j] = *(const short8*)(Vf + gV[j] + tn * TS);
            }
        }

        // ---- fixed-max softmax (exp2 domain) + packed repack to permuted-k
        // A-frag: slot j = mt*4+i holds key 16*(j>>2) + 4*quad + (j&3).
        // v_cvt_pkrtz packs pairs; v_dot2_f32_f16 accumulates the row-sum.
        half8 a8[2];
        #pragma unroll
        for (int nq = 0; nq < 2; ++nq) {
            union { half8 v; fp16x2 h[4]; } a;
            float ls = lac[nq];
            #pragma unroll
            for (int mt = 0; mt < 2; ++mt)
                #pragma unroll
                for (int ip = 0; ip < 2; ++ip) {
                    const float p0 = EXP2F(sf[mt][nq][2 * ip]);
                    const float p1 = EXP2F(sf[mt][nq][2 * ip + 1]);
                    const fp16x2 h2 = __builtin_amdgcn_cvt_pkrtz(p0, p1);
                    a.h[mt * 2 + ip] = h2;
                    ls = __builtin_amdgcn_fdot2(h2, ones, ls, false);
                }
            lac[nq] = ls;
            a8[nq] = a.v;
        }

        // ---- PV: baked-permutation V B-frags, single b128 each
        #pragma unroll
        for (int nt = 0; nt < 8; ++nt) {
            const half8 vfr = *(const half8*)(ldsu + bo + vOff[nt]);
            #pragma unroll
            for (int nq = 0; nq < 2; ++nq)
                O_[nq][nt] = MFMAH(a8[nq], vfr, O_[nq][nt]);
        }

        __syncthreads();   // tile r+1 visible; peers done reading buffer r
    }

    // ---- epilogue: merge ks partials ------------------------------------
    // l partials: reduce across quads, publish per (hh,ks,stripe,row)
    {
        float s0 = lac[0], s1 = lac[1];
        s0 += __shfl_xor(s0, 16); s0 += __shfl_xor(s0, 32);
        s1 += __shfl_xor(s1, 16); s1 += __shfl_xor(s1, 32);
        if (quad == 0) {
            sm.e.lbuf[hh][ks][stripe][lc]      = s0;
            sm.e.lbuf[hh][ks][stripe][16 + lc] = s1;
        }
    }
    __syncthreads();
    // per-row coefficient from merged l (sign/lam folded for hh1)
    float coef[2][4];
    #pragma unroll
    for (int nq = 0; nq < 2; ++nq)
        #pragma unroll
        for (int i = 0; i < 4; ++i) {
            const int row = nq * 16 + quad * 4 + i;
            const float lt = sm.e.lbuf[hh][0][stripe][row] +
                             sm.e.lbuf[hh][1][stripe][row];
            coef[nq][i] = (hh == 0) ? (1.f / lt) : (-lam / lt);
        }
    __syncthreads();
    // 4-phase accumulation of scaled partials into epi
    const int pid = hh * 2 + ks;
    #pragma unroll
    for (int p = 0; p < 4; ++p) {
        if (pid == p) {
            #pragma unroll
            for (int nq = 0; nq < 2; ++nq)
                #pragma unroll
                for (int i = 0; i < 4; ++i) {
                    const int row = nq * 16 + quad * 4 + i;
                    #pragma unroll
                    for (int nt = 0; nt < 8; ++nt) {
                        const int col = nt * 16 + lc;
                        const float v = O_[nq][nt][i] * coef[nq][i];
                        if (p == 0) sm.e.epi[stripe][row][col] = v;
                        else        sm.e.epi[stripe][row][col] += v;
                    }
                }
        }
        __syncthreads();
    }
    // RMS + store: wave wv handles rows wv*8 .. wv*8+7 (8 lanes per row)
    {
        const int r0 = wv * 8 + (lane >> 3);
        const int st = r0 >> 5, ri = r0 & 31;
        const int e0 = (lane & 7) * 16;
        float x[16];
        float ssq = 0.f;
        #pragma unroll
        for (int m = 0; m < 16; m += 4) {
            const float4 t4 = *(const float4*)&sm.e.epi[st][ri][e0 + m];
            x[m] = t4.x; x[m + 1] = t4.y; x[m + 2] = t4.z; x[m + 3] = t4.w;
            ssq += t4.x * t4.x + t4.y * t4.y + t4.z * t4.z + t4.w * t4.w;
        }
        ssq += __shfl_xor(ssq, 1);
        ssq += __shfl_xor(ssq, 2);
        ssq += __shfl_xor(ssq, 4);
        const float rsq = rsqrtf(ssq * (1.f / 128.f) + 1e-5f) * OUT_SCALE;
        const int rowg = qt * TQ + r0;
        const size_t base =
            ((size_t)b * NT + rowg) * (size_t)(8 * DV) + (size_t)h * DV;
        #pragma unroll
        for (int m = 0; m < 16; m += 4) {
            const float4 w4 = *(const float4*)(Wg + e0 + m);
            float4 o4;
            o4.x = x[m] * rsq * w4.x;
            o4.y = x[m + 1] * rsq * w4.y;
            o4.z = x[m + 2] * rsq * w4.z;
            o4.w = x[m + 3] * rsq * w4.w;
            *(float4*)(Outg + base + e0 + m) = o4;
        }
    }
}

// ------------------------ fallback (in-kernel conversion, bf16 split) --------
__device__ __forceinline__ unsigned short f2bf(float x) {
    unsigned u = __float_as_uint(x);
    return (unsigned short)((u + 0x7fffu + ((u >> 16) & 1u)) >> 16);
}
__device__ __forceinline__ float bf2f(unsigned short h) {
    return __uint_as_float(((unsigned)h) << 16);
}

struct SmemB {
    union {
        struct {
            short8 kh[2][264];
            short8 kl[2][264];
            short8 vh[516];
            short8 vl[516];
            unsigned short ph[2][2560];
            unsigned short pl[2][2560];
        } L;
        float epi[2][32][132];
    };
};

__global__ __launch_bounds__(256, 2) void diffattn_fb(
    const float* __restrict__ Qg, const float* __restrict__ Kg,
    const float* __restrict__ Vg,
    const float* __restrict__ lq1, const float* __restrict__ lk1,
    const float* __restrict__ lq2, const float* __restrict__ lk2,
    const float* __restrict__ Wg, float* __restrict__ Outg)
{
    __shared__ SmemB sm;
    const int tid = threadIdx.x;
    const int wv = tid >> 6, lane = tid & 63;
    const int quad = lane >> 4, lc = lane & 15;
    const int stripe = wv & 1, hh = wv >> 1;
    const int qt = blockIdx.x, bh = blockIdx.y;
    const int b = bh >> 3, h = bh & 7;
    const size_t koff0 = ((size_t)(b * 16 + 2 * h)) * NT * D;
    const size_t voff  = ((size_t)(b * 8 + h)) * NT * DV;
    float t1 = 0.f, t2 = 0.f;
    for (int i = 0; i < D; ++i) {
        t1 = fmaf(lq1[i], lk1[i], t1);
        t2 = fmaf(lq2[i], lk2[i], t2);
    }
    const float lam = __expf(t1) - __expf(t2) + LAMBDA_INIT;
    short8 qfh[2][2], qfl[2][2];
    {
        const size_t qhead = ((size_t)(b * 16 + 2 * h + hh)) * NT * D;
        #pragma unroll
        for (int mt = 0; mt < 2; ++mt)
            #pragma unroll
            for (int k0 = 0; k0 < 2; ++k0) {
                const int row = qt * TQ + stripe * 32 + mt * 16 + lc;
                const int d0  = k0 * 32 + quad * 8;
                const float4 x = *(const float4*)(Qg + qhead + (size_t)row * D + d0);
                const float4 y = *(const float4*)(Qg + qhead + (size_t)row * D + d0 + 4);
                float f[8] = {x.x, x.y, x.z, x.w, y.x, y.y, y.z, y.w};
                #pragma unroll
                for (int j = 0; j < 8; ++j) {
                    const float v = f[j] * 0.125f;
                    const unsigned short hi = f2bf(v);
                    qfh[mt][k0][j] = (short)hi;
                    qfl[mt][k0][j] = (short)f2bf(v - bf2f(hi));
                }
            }
    }
    f32x4 O_[2][8];
    #pragma unroll
    for (int mt = 0; mt < 2; ++mt)
        #pragma unroll
        for (int nt = 0; nt < 8; ++nt) O_[mt][nt] = (f32x4){0.f, 0.f, 0.f, 0.f};
    float m_[2][4], l_[2][4], a_[2][4];
    #pragma unroll
    for (int mt = 0; mt < 2; ++mt)
        #pragma unroll
        for (int i = 0; i < 4; ++i) { m_[mt][i] = -1e30f; l_[mt][i] = 0.f; }
    const int s_hh = tid >> 7;
    const int s_n  = (tid >> 2) & 31;
    const int s_d0 = (tid & 3) * 16;
    const int s_e0 = tid & 31;
    const int s_s0 = ((tid >> 5) & 7) * 4;
    const int s_sb = s_s0 >> 3;
    const int s_hs = (s_s0 & 4) ? 1 : 0;
    for (int kt = 0; kt < NT / TS; ++kt) {
        const int kb = kt * TS;
        __syncthreads();
        {
            const float* kp = Kg + koff0 + (size_t)s_hh * NT * D +
                              (size_t)(kb + s_n) * D + s_d0;
            const float4 x0 = ((const float4*)kp)[0];
            const float4 x1 = ((const float4*)kp)[1];
            const float4 x2 = ((const float4*)kp)[2];
            const float4 x3 = ((const float4*)kp)[3];
            float f[16] = {x0.x, x0.y, x0.z, x0.w, x1.x, x1.y, x1.z, x1.w,
                           x2.x, x2.y, x2.z, x2.w, x3.x, x3.y, x3.z, x3.w};
            short8 c0h, c0l, c1h, c1l;
            #pragma unroll
            for (int j = 0; j < 8; ++j) {
                unsigned short hi = f2bf(f[j]);
                c0h[j] = (short)hi; c0l[j] = (short)f2bf(f[j] - bf2f(hi));
                hi = f2bf(f[8 + j]);
                c1h[j] = (short)hi; c1l[j] = (short)f2bf(f[8 + j] - bf2f(hi));
            }
            const int db0 = s_d0 >> 3;
            sm.L.kh[s_hh][db0 * 33 + s_n]       = c0h;
            sm.L.kl[s_hh][db0 * 33 + s_n]       = c0l;
            sm.L.kh[s_hh][(db0 + 1) * 33 + s_n] = c1h;
            sm.L.kl[s_hh][(db0 + 1) * 33 + s_n] = c1l;
        }
        {
            #pragma unroll
            for (int j = 0; j < 4; ++j) {
                const int e = s_e0 + 32 * j;
                float f[4];
                #pragma unroll
                for (int i = 0; i < 4; ++i)
                    f[i] = Vg[voff + (size_t)(kb + s_s0 + i) * DV + e];
                short4v hi4, lo4;
                #pragma unroll
                for (int i = 0; i < 4; ++i) {
                    const unsigned short hi = f2bf(f[i]);
                    hi4[i] = (short)hi;
                    lo4[i] = (short)f2bf(f[i] - bf2f(hi));
                }
                ((short4v*)&sm.L.vh[s_sb * 129 + e])[s_hs] = hi4;
                ((short4v*)&sm.L.vl[s_sb * 129 + e])[s_hs] = lo4;
            }
        }
        __syncthreads();
        f32x4 s_f[2][2];
        #pragma unroll
        for (int mt = 0; mt < 2; ++mt)
            #pragma unroll
            for (int nt = 0; nt < 2; ++nt) s_f[mt][nt] = (f32x4){0.f, 0.f, 0.f, 0.f};
        #pragma unroll
        for (int k0 = 0; k0 < 2; ++k0)
            #pragma unroll
            for (int nt = 0; nt < 2; ++nt) {
                const short8 kh = sm.L.kh[hh][(4 * k0 + quad) * 33 + nt * 16 + lc];
                const short8 kl = sm.L.kl[hh][(4 * k0 + quad) * 33 + nt * 16 + lc];
                #pragma unroll
                for (int mt = 0; mt < 2; ++mt) {
                    s_f[mt][nt] = MFMA16(qfh[mt][k0], kh, s_f[mt][nt]);
                    s_f[mt][nt] = MFMA16(qfl[mt][k0], kh, s_f[mt][nt]);
                    s_f[mt][nt] = MFMA16(qfh[mt][k0], kl, s_f[mt][nt]);
                }
            }
        #pragma unroll
        for (int mt = 0; mt < 2; ++mt)
            #pragma unroll
            for (int i = 0; i < 4; ++i) {
                const float v0 = s_f[mt][0][i], v1 = s_f[mt][1][i];
                float mx = fmaxf(v0, v1);
                mx = fmaxf(mx, __shfl_xor(mx, 1));
                mx = fmaxf(mx, __shfl_xor(mx, 2));
                mx = fmaxf(mx, __shfl_xor(mx, 4));
                mx = fmaxf(mx, __shfl_xor(mx, 8));
                const float mn = fmaxf(m_[mt][i], mx);
                const float al = __expf(m_[mt][i] - mn);
                const float p0 = __expf(v0 - mn);
                const float p1 = __expf(v1 - mn);
                float rs = p0 + p1;
                rs += __shfl_xor(rs, 1);
                rs += __shfl_xor(rs, 2);
                rs += __shfl_xor(rs, 4);
                rs += __shfl_xor(rs, 8);
                l_[mt][i] = l_[mt][i] * al + rs;
                m_[mt][i] = mn;
                a_[mt][i] = al;
                const int r = stripe * 32 + mt * 16 + quad * 4 + i;
                const unsigned short h0 = f2bf(p0);
                sm.L.ph[hh][r * 40 + lc]      = h0;
                sm.L.pl[hh][r * 40 + lc]      = f2bf(p0 - bf2f(h0));
                const unsigned short h1 = f2bf(p1);
                sm.L.ph[hh][r * 40 + 16 + lc] = h1;
                sm.L.pl[hh][r * 40 + 16 + lc] = f2bf(p1 - bf2f(h1));
            }
        __syncthreads();
        #pragma unroll
        for (int mt = 0; mt < 2; ++mt)
            #pragma unroll
            for (int nt = 0; nt < 8; ++nt)
                #pragma unroll
                for (int i = 0; i < 4; ++i) O_[mt][nt][i] *= a_[mt][i];
        short8 pah[2], pal[2];
        #pragma unroll
        for (int mt = 0; mt < 2; ++mt) {
            const int r = stripe * 32 + mt * 16 + lc;
            pah[mt] = *(const short8*)&sm.L.ph[hh][r * 40 + quad * 8];
            pal[mt] = *(const short8*)&sm.L.pl[hh][r * 40 + quad * 8];
        }
        #pragma unroll
        for (int nt = 0; nt < 8; ++nt) {
            const short8 vh = sm.L.vh[quad * 129 + nt * 16 + lc];
            const short8 vl = sm.L.vl[quad * 129 + nt * 16 + lc];
            #pragma unroll
            for (int mt = 0; mt < 2; ++mt) {
                O_[mt][nt] = MFMA16(pah[mt], vh, O_[mt][nt]);
                O_[mt][nt] = MFMA16(pal[mt], vh, O_[mt][nt]);
                O_[mt][nt] = MFMA16(pah[mt], vl, O_[mt][nt]);
            }
        }
    }
    __syncthreads();
    if (hh == 1) {
        #pragma unroll
        for (int mt = 0; mt < 2; ++mt)
            #pragma unroll
            for (int i = 0; i < 4; ++i) {
                const float inv = lam / l_[mt][i];
                const int r = mt * 16 + quad * 4 + i;
                #pragma unroll
                for (int nt = 0; nt < 8; ++nt)
                    sm.epi[stripe][r][nt * 16 + lc] = O_[mt][nt][i] * inv;
            }
    }
    __syncthreads();
    if (hh == 0) {
        float wvv[8];
        #pragma unroll
        for (int nt = 0; nt < 8; ++nt) wvv[nt] = Wg[nt * 16 + lc];
        #pragma unroll
        for (int mt = 0; mt < 2; ++mt)
            #pragma unroll
            for (int i = 0; i < 4; ++i) {
                const float inv1 = 1.f / l_[mt][i];
                const int r = mt * 16 + quad * 4 + i;
                float od[8];
                float ss = 0.f;
                #pragma unroll
                for (int nt = 0; nt < 8; ++nt) {
                    od[nt] = O_[mt][nt][i] * inv1 - sm.epi[stripe][r][nt * 16 + lc];
                    ss = fmaf(od[nt], od[nt], ss);
                }
                ss += __shfl_xor(ss, 1);
                ss += __shfl_xor(ss, 2);
                ss += __shfl_xor(ss, 4);
                ss += __shfl_xor(ss, 8);
                const float rsq = rsqrtf(ss * (1.f / 128.f) + 1e-5f) * OUT_SCALE;
                const int rowg = qt * TQ + stripe * 32 + r;
                const size_t base =
                    ((size_t)b * NT + rowg) * (size_t)(8 * DV) + (size_t)h * DV;
                #pragma unroll
                for (int nt = 0; nt < 8; ++nt)
                    Outg[base + nt * 16 + lc] = od[nt] * rsq * wvv[nt];
            }
    }
}

extern "C" void kernel_launch(void* const* d_in, const int* in_sizes, int n_in,
                              void* d_out, int out_size, void* d_ws, size_t ws_size,
                              hipStream_t stream) {
    const float* Q   = (const float*)d_in[0];
    const float* K   = (const float*)d_in[1];
    const float* V   = (const float*)d_in[2];
    const float* lq1 = (const float*)d_in[3];
    const float* lk1 = (const float*)d_in[4];
    const float* lq2 = (const float*)d_in[5];
    const float* lk2 = (const float*)d_in[6];
    const float* W   = (const float*)d_in[7];
    float* Out = (float*)d_out;
    const size_t NEED = 2ull * 4194304ull * sizeof(u16) + 16;   // 16.8 MB
    if (ws_size >= NEED) {
        u16*   Kf   = (u16*)d_ws;
        u16*   Vf   = Kf + 4194304;
        float* lamw = (float*)(Vf + 4194304);
        prep_kv<<<2561, 256, 0, stream>>>(K, V, lq1, lk1, lq2, lk2, Kf, Vf, lamw);
        diffattn_mfma11<<<dim3(NT / TQ, 16), 512, 0, stream>>>(
            Q, Kf, Vf, lamw, W, Out);
    } else {
        diffattn_fb<<<dim3(NT / TQ, 16), 256, 0, stream>>>(
            Q, K, V, lq1, lk1, lq2, lk2, W, Out);
    }
}

// Round 2
// 169.592 us; speedup vs baseline: 1.0937x; 1.0937x over previous
//
#include <hip/hip_runtime.h>
#include <math.h>

// DiffAttn flash R12 — R11 post-mortem: commit-after-QK spilled ~14 VGPR/thread
// (WRITE_SIZE 17.4->31.7MB = scratch). R12 removes register staging entirely:
// global_load_lds width-16 with linear LDS dest + inverse-swizzled per-lane
// GLOBAL source (m173 pattern) -> LDS image identical to R10/R11, read side
// untouched. One barrier/round: issue glld(tile r+1 -> alt) at round start
// (post-barrier, alt readers done), compute on cur, __syncthreads' implicit
// vmcnt(0) drain completes the loads with a full round of flight time.
// Softmax VALU diet kept: exp2-domain (log2e folded into Q prescale),
// v_cvt_pkrtz pack, v_dot2_f32_f16 row-sum.
// B=2, 8 head-pairs, T=S=2048, D=64, DV=128, fp32 in/out.

#define NT    2048
#define D     64
#define DV    128
#define TQ    64
#define TS    32
#define NROUND (NT / (2 * TS))   // 32 rounds, 2 tiles/round (one per ks group)

#define LAMBDA_INIT 0.70082066706704814f   // 0.8 - 0.6*exp(-1.8)
#define OUT_SCALE   0.29917933293295186f   // 1 - LAMBDA_INIT
#define QSCALE      0.18033688011112042f   // 0.125 * log2(e): softmax in exp2 domain

typedef __attribute__((ext_vector_type(8)))  short    short8;
typedef __attribute__((ext_vector_type(4)))  short    short4v;
typedef __attribute__((ext_vector_type(8)))  _Float16 half8;
typedef __attribute__((ext_vector_type(2)))  __fp16   fp16x2;
typedef __attribute__((ext_vector_type(4)))  float    f32x4;
typedef unsigned short u16;
typedef unsigned int   u32;

#define MFMAH(a, b, c)  __builtin_amdgcn_mfma_f32_16x16x32_f16(a, b, c, 0, 0, 0)
#define MFMA16(a, b, c) __builtin_amdgcn_mfma_f32_16x16x32_bf16(a, b, c, 0, 0, 0)

#if __has_builtin(__builtin_amdgcn_exp2f)
#define EXP2F(x) __builtin_amdgcn_exp2f(x)
#else
#define EXP2F(x) exp2f(x)
#endif

union Hu { half8 v; _Float16 e[8]; u16 s[8]; short8 sv; };

__device__ __forceinline__ u16 f2h(float x) {
    Hu u; u.e[0] = (_Float16)x; return u.s[0];
}

// async global->LDS, 16B per lane; dst is wave-uniform base, lane i lands at
// dst + i*16. Source address is per-lane (carries the inverse swizzle).
__device__ __forceinline__ void glds16(const u16* g, const u16* l) {
    __builtin_amdgcn_global_load_lds(
        (const __attribute__((address_space(1))) void*)g,
        (__attribute__((address_space(3))) void*)l, 16, 0, 0);
}

// ---------------- prep_kv: one dispatch for K-convert + lambda + V-transform
// blocks 0..2047: K f32 -> fp16.  block 2048: lambda.  blocks 2049..2560:
// V -> fp16 transposed [e][s'] with baked 16x16 kappa permutation: within each
// 32-key group, chunk c (c=0..3) slot j holds key 4c + (j&3) + 16*(j>>2).
__global__ __launch_bounds__(256) void prep_kv(
    const float* __restrict__ Kg, const float* __restrict__ Vg,
    const float* __restrict__ lq1, const float* __restrict__ lk1,
    const float* __restrict__ lq2, const float* __restrict__ lk2,
    u16* __restrict__ Kf, u16* __restrict__ Vf, float* __restrict__ lamw)
{
    __shared__ u16 th[64 * 136];   // [e][s] tile, stride 136 (V path only)
    const int bid = blockIdx.x;
    const int t   = threadIdx.x;
    if (bid < 2048) {
        const int idx = (bid * 256 + t) * 8;
        const float4 a = *(const float4*)(Kg + idx);
        const float4 b = *(const float4*)(Kg + idx + 4);
        Hu H;
        H.e[0] = (_Float16)a.x; H.e[1] = (_Float16)a.y;
        H.e[2] = (_Float16)a.z; H.e[3] = (_Float16)a.w;
        H.e[4] = (_Float16)b.x; H.e[5] = (_Float16)b.y;
        H.e[6] = (_Float16)b.z; H.e[7] = (_Float16)b.w;
        *(short8*)(Kf + idx) = H.sv;
        return;
    }
    if (bid == 2048) {
        if (t == 0) {
            float t1 = 0.f, t2 = 0.f;
            for (int i = 0; i < D; ++i) {
                t1 = fmaf(lq1[i], lk1[i], t1);
                t2 = fmaf(lq2[i], lk2[i], t2);
            }
            lamw[0] = __expf(t1) - __expf(t2) + LAMBDA_INIT;
        }
        return;
    }
    const int i  = bid - 2049;
    const int bh = i >> 5;
    const int eb = (i >> 4) & 1;
    const int sb = i & 15;
    const size_t vbase = (size_t)bh * NT * DV + (size_t)sb * 128 * DV + eb * 64;
    {
        const int r0 = t >> 4;
        const int c4 = (t & 15) * 4;
        #pragma unroll
        for (int rr = 0; rr < 8; ++rr) {
            const int row = r0 + rr * 16;
            const float4 x = *(const float4*)(Vg + vbase + (size_t)row * DV + c4);
            th[(c4 + 0) * 136 + row] = f2h(x.x);
            th[(c4 + 1) * 136 + row] = f2h(x.y);
            th[(c4 + 2) * 136 + row] = f2h(x.z);
            th[(c4 + 3) * 136 + row] = f2h(x.w);
        }
    }
    __syncthreads();
    const int e  = t >> 2;
    const int g  = t & 3;          // 32-key group 0..3 (of the 128-s block)
    const size_t orow = ((size_t)bh * DV + eb * 64 + e) * NT + sb * 128;
    #pragma unroll
    for (int c = 0; c < 4; ++c) {  // storage chunk within group
        Hu o;
        #pragma unroll
        for (int j = 0; j < 8; ++j)
            o.s[j] = th[e * 136 + g * 32 + 4 * c + (j & 3) + 16 * (j >> 2)];
        *(short8*)(Vf + orow + g * 32 + c * 8) = o.sv;   // 64B contig/thread
    }
}

// --------------------------------- flash kernel ------------------------------
// LDS: two 32KB staging buffers (double-buffered by round parity), filled via
// global_load_lds. Chunk layout (16B chunks, identical to R10):
//   K group ks: [ks*512 + hhs*256 + n*8 + (db ^ (n&7))]
//   V group ks: [1024 + ks*512 + e*4 + (u ^ ((e>>1)&3))]
// glld writes linearly; the swizzle is baked into the per-lane SOURCE address.
struct SmemF {
    union {
        short8 c[4096];                    // 65536 B (2 x 32KB round buffers)
        struct {
            float epi[2][32][132];         // 33792 B
            float lbuf[2][2][2][32];       //  1024 B  [hh][ks][stripe][row]
        } e;
    };
};

__global__ __launch_bounds__(512, 4) void diffattn_mfma12(
    const float* __restrict__ Qg,
    const u16* __restrict__ Kf, const u16* __restrict__ Vf,
    const float* __restrict__ lamw,
    const float* __restrict__ Wg, float* __restrict__ Outg)
{
    __shared__ SmemF sm;

    const int tid    = threadIdx.x;
    const int wv     = tid >> 6;
    const int lane   = tid & 63;
    const int quad   = lane >> 4;
    const int lc     = lane & 15;
    const int stripe = wv & 1;          // 32-row half of the 64-row q-tile
    const int hh     = (wv >> 1) & 1;   // half-head (softmax 1 vs 2)
    const int ks     = wv >> 2;         // key-split group: tiles 2r+ks
    const int wig    = wv & 3;          // wave index within ks group
    const int qt     = blockIdx.x;
    const int bh     = blockIdx.y;
    const int b      = bh >> 3, h = bh & 7;

    const int head2b = b * 16 + 2 * h;
    const int bh8    = b * 8 + h;
    const float lam  = lamw[0];

    // Q B-frags (B[k=d][n=qrow]: n=lc, k=quad*8+j within k0*32), pre-scaled by
    // 0.125*log2e so softmax is a bare v_exp_f32 in exp2 domain.
    half8 qf[2][2];
    {
        const size_t qhead = (size_t)(head2b + hh) * NT * D;
        #pragma unroll
        for (int nq = 0; nq < 2; ++nq) {
            const int row = qt * TQ + stripe * 32 + nq * 16 + lc;
            #pragma unroll
            for (int k0 = 0; k0 < 2; ++k0) {
                const int d0 = k0 * 32 + quad * 8;
                const float4 x = *(const float4*)(Qg + qhead + (size_t)row * D + d0);
                const float4 y = *(const float4*)(Qg + qhead + (size_t)row * D + d0 + 4);
                Hu q;
                q.e[0] = (_Float16)(x.x * QSCALE); q.e[1] = (_Float16)(x.y * QSCALE);
                q.e[2] = (_Float16)(x.z * QSCALE); q.e[3] = (_Float16)(x.w * QSCALE);
                q.e[4] = (_Float16)(y.x * QSCALE); q.e[5] = (_Float16)(y.y * QSCALE);
                q.e[6] = (_Float16)(y.z * QSCALE); q.e[7] = (_Float16)(y.w * QSCALE);
                qf[nq][k0] = q.v;
            }
        }
    }

    f32x4 O_[2][8];   // [nq][nt]: row = nq*16+quad*4+i, e = nt*16+lc
    #pragma unroll
    for (int nq = 0; nq < 2; ++nq)
        #pragma unroll
        for (int nt = 0; nt < 8; ++nt) O_[nq][nt] = (f32x4){0.f, 0.f, 0.f, 0.f};
    float lac[2] = {0.f, 0.f};

    // staging: group ks fills its own 8KB K + 8KB V per round via 4 glld
    // instructions/wave. LDS dest is linear (wave-uniform base + lane*16);
    // the inverse of the chunk swizzle is baked into the per-lane source.
    u32 kSrc[2], vSrc[2];   // per-lane element offsets into Kf/Vf (tile 0)
    u32 kLds[2], vLds[2];   // wave-uniform byte offsets into buffer 0
    #pragma unroll
    for (int t = 0; t < 2; ++t) {
        const int p   = (wig * 2 + t) * 64 + lane;   // K chunk position 0..511
        const int hhs = p >> 8;
        const int n   = (p >> 3) & 31;
        const int db  = (p & 7) ^ (n & 7);           // inverse swizzle (XOR involution)
        kSrc[t] = (u32)(((head2b + hhs) * NT + n) * D + db * 8);
        kLds[t] = (u32)((ks * 512 + (wig * 2 + t) * 64) * 16);
        const int e = p >> 2;
        const int u = (p & 3) ^ ((e >> 1) & 3);      // inverse swizzle
        vSrc[t] = (u32)((bh8 * DV + e) * NT + u * 8);
        vLds[t] = (u32)((1024 + ks * 512 + (wig * 2 + t) * 64) * 16);
    }
    const u16* ldsu = (const u16*)&sm.c[0];

    // prologue: stage tile ks into buffer 0; __syncthreads drains vmcnt.
    #pragma unroll
    for (int t = 0; t < 2; ++t) {
        glds16(Kf + kSrc[t] + (u32)ks * (TS * D), ldsu + (kLds[t] >> 1));
        glds16(Vf + vSrc[t] + (u32)ks * TS,       ldsu + (vLds[t] >> 1));
    }
    __syncthreads();

    // frag LDS offsets (u16 units, within one round buffer)
    u32 kOff[2][2];
    #pragma unroll
    for (int k0 = 0; k0 < 2; ++k0)
        #pragma unroll
        for (int mt = 0; mt < 2; ++mt)
            kOff[k0][mt] = (u32)((ks * 512 + hh * 256 + (mt * 16 + lc) * 8 +
                                  ((4 * k0 + quad) ^ (lc & 7))) * 8);
    u32 vOff[8];
    {
        const int swzv = quad ^ ((lc >> 1) & 3);
        #pragma unroll
        for (int nt = 0; nt < 8; ++nt)
            vOff[nt] = (u32)((1024 + ks * 512 + (nt * 16 + lc) * 4 + swzv) * 8);
    }

    const fp16x2 ones = {(__fp16)1.f, (__fp16)1.f};

    for (int r = 0; r < NROUND; ++r) {
        const u32 bo = ((u32)(r & 1)) << 14;        // current buffer, u16 units

        // ---- issue async stage of tile r+1 into the ALTERNATE buffer.
        // Post-barrier: all reads of that buffer (round r-1) are done. The
        // end-of-round __syncthreads' implicit vmcnt(0) is the completion
        // guarantee — a full round of flight time.
        if (r < NROUND - 1) {
            const u32 tn = (u32)(2 * (r + 1) + ks);
            const u32 ab = ((u32)((r + 1) & 1)) << 14;   // alt buffer, u16 units
            #pragma unroll
            for (int t = 0; t < 2; ++t) {
                glds16(Kf + kSrc[t] + tn * (TS * D), ldsu + ab + (kLds[t] >> 1));
                glds16(Vf + vSrc[t] + tn * TS,       ldsu + ab + (vLds[t] >> 1));
            }
        }

        // ---- S^T = K·Q^T: key = mt*16 + quad*4 + i, qrow = nq*16 + lc
        f32x4 sf[2][2];
        #pragma unroll
        for (int mt = 0; mt < 2; ++mt)
            #pragma unroll
            for (int nq = 0; nq < 2; ++nq) sf[mt][nq] = (f32x4){0.f, 0.f, 0.f, 0.f};
        #pragma unroll
        for (int k0 = 0; k0 < 2; ++k0) {
            #pragma unroll
            for (int mt = 0; mt < 2; ++mt) {
                const half8 kfr = *(const half8*)(ldsu + bo + kOff[k0][mt]);
                #pragma unroll
                for (int nq = 0; nq < 2; ++nq)
                    sf[mt][nq] = MFMAH(kfr, qf[nq][k0], sf[mt][nq]);
            }
        }

        // ---- fixed-max softmax (exp2 domain) + packed repack to permuted-k
        // A-frag: slot j = mt*4+i holds key 16*(j>>2) + 4*quad + (j&3).
        half8 a8[2];
        #pragma unroll
        for (int nq = 0; nq < 2; ++nq) {
            union { half8 v; fp16x2 h[4]; } a;
            float ls = lac[nq];
            #pragma unroll
            for (int mt = 0; mt < 2; ++mt)
                #pragma unroll
                for (int ip = 0; ip < 2; ++ip) {
                    const float p0 = EXP2F(sf[mt][nq][2 * ip]);
                    const float p1 = EXP2F(sf[mt][nq][2 * ip + 1]);
                    const fp16x2 h2 = __builtin_amdgcn_cvt_pkrtz(p0, p1);
                    a.h[mt * 2 + ip] = h2;
                    ls = __builtin_amdgcn_fdot2(h2, ones, ls, false);
                }
            lac[nq] = ls;
            a8[nq] = a.v;
        }

        // ---- PV: baked-permutation V B-frags, single b128 each
        #pragma unroll
        for (int nt = 0; nt < 8; ++nt) {
            const half8 vfr = *(const half8*)(ldsu + bo + vOff[nt]);
            #pragma unroll
            for (int nq = 0; nq < 2; ++nq)
                O_[nq][nt] = MFMAH(a8[nq], vfr, O_[nq][nt]);
        }

        __syncthreads();   // drains glld(tile r+1); peers done reading cur
    }

    // ---- epilogue: merge ks partials ------------------------------------
    // l partials: reduce across quads, publish per (hh,ks,stripe,row)
    {
        float s0 = lac[0], s1 = lac[1];
        s0 += __shfl_xor(s0, 16); s0 += __shfl_xor(s0, 32);
        s1 += __shfl_xor(s1, 16); s1 += __shfl_xor(s1, 32);
        if (quad == 0) {
            sm.e.lbuf[hh][ks][stripe][lc]      = s0;
            sm.e.lbuf[hh][ks][stripe][16 + lc] = s1;
        }
    }
    __syncthreads();
    // per-row coefficient from merged l (sign/lam folded for hh1)
    float coef[2][4];
    #pragma unroll
    for (int nq = 0; nq < 2; ++nq)
        #pragma unroll
        for (int i = 0; i < 4; ++i) {
            const int row = nq * 16 + quad * 4 + i;
            const float lt = sm.e.lbuf[hh][0][stripe][row] +
                             sm.e.lbuf[hh][1][stripe][row];
            coef[nq][i] = (hh == 0) ? (1.f / lt) : (-lam / lt);
        }
    __syncthreads();
    // 4-phase accumulation of scaled partials into epi
    const int pid = hh * 2 + ks;
    #pragma unroll
    for (int p = 0; p < 4; ++p) {
        if (pid == p) {
            #pragma unroll
            for (int nq = 0; nq < 2; ++nq)
                #pragma unroll
                for (int i = 0; i < 4; ++i) {
                    const int row = nq * 16 + quad * 4 + i;
                    #pragma unroll
                    for (int nt = 0; nt < 8; ++nt) {
                        const int col = nt * 16 + lc;
                        const float v = O_[nq][nt][i] * coef[nq][i];
                        if (p == 0) sm.e.epi[stripe][row][col] = v;
                        else        sm.e.epi[stripe][row][col] += v;
                    }
                }
        }
        __syncthreads();
    }
    // RMS + store: wave wv handles rows wv*8 .. wv*8+7 (8 lanes per row)
    {
        const int r0 = wv * 8 + (lane >> 3);
        const int st = r0 >> 5, ri = r0 & 31;
        const int e0 = (lane & 7) * 16;
        float x[16];
        float ssq = 0.f;
        #pragma unroll
        for (int m = 0; m < 16; m += 4) {
            const float4 t4 = *(const float4*)&sm.e.epi[st][ri][e0 + m];
            x[m] = t4.x; x[m + 1] = t4.y; x[m + 2] = t4.z; x[m + 3] = t4.w;
            ssq += t4.x * t4.x + t4.y * t4.y + t4.z * t4.z + t4.w * t4.w;
        }
        ssq += __shfl_xor(ssq, 1);
        ssq += __shfl_xor(ssq, 2);
        ssq += __shfl_xor(ssq, 4);
        const float rsq = rsqrtf(ssq * (1.f / 128.f) + 1e-5f) * OUT_SCALE;
        const int rowg = qt * TQ + r0;
        const size_t base =
            ((size_t)b * NT + rowg) * (size_t)(8 * DV) + (size_t)h * DV;
        #pragma unroll
        for (int m = 0; m < 16; m += 4) {
            const float4 w4 = *(const float4*)(Wg + e0 + m);
            float4 o4;
            o4.x = x[m] * rsq * w4.x;
            o4.y = x[m + 1] * rsq * w4.y;
            o4.z = x[m + 2] * rsq * w4.z;
            o4.w = x[m + 3] * rsq * w4.w;
            *(float4*)(Outg + base + e0 + m) = o4;
        }
    }
}

// ------------------------ fallback (in-kernel conversion, bf16 split) --------
__device__ __forceinline__ unsigned short f2bf(float x) {
    unsigned u = __float_as_uint(x);
    return (unsigned short)((u + 0x7fffu + ((u >> 16) & 1u)) >> 16);
}
__device__ __forceinline__ float bf2f(unsigned short h) {
    return __uint_as_float(((unsigned)h) << 16);
}

struct SmemB {
    union {
        struct {
            short8 kh[2][264];
            short8 kl[2][264];
            short8 vh[516];
            short8 vl[516];
            unsigned short ph[2][2560];
            unsigned short pl[2][2560];
        } L;
        float epi[2][32][132];
    };
};

__global__ __launch_bounds__(256, 2) void diffattn_fb(
    const float* __restrict__ Qg, const float* __restrict__ Kg,
    const float* __restrict__ Vg,
    const float* __restrict__ lq1, const float* __restrict__ lk1,
    const float* __restrict__ lq2, const float* __restrict__ lk2,
    const float* __restrict__ Wg, float* __restrict__ Outg)
{
    __shared__ SmemB sm;
    const int tid = threadIdx.x;
    const int wv = tid >> 6, lane = tid & 63;
    const int quad = lane >> 4, lc = lane & 15;
    const int stripe = wv & 1, hh = wv >> 1;
    const int qt = blockIdx.x, bh = blockIdx.y;
    const int b = bh >> 3, h = bh & 7;
    const size_t koff0 = ((size_t)(b * 16 + 2 * h)) * NT * D;
    const size_t voff  = ((size_t)(b * 8 + h)) * NT * DV;
    float t1 = 0.f, t2 = 0.f;
    for (int i = 0; i < D; ++i) {
        t1 = fmaf(lq1[i], lk1[i], t1);
        t2 = fmaf(lq2[i], lk2[i], t2);
    }
    const float lam = __expf(t1) - __expf(t2) + LAMBDA_INIT;
    short8 qfh[2][2], qfl[2][2];
    {
        const size_t qhead = ((size_t)(b * 16 + 2 * h + hh)) * NT * D;
        #pragma unroll
        for (int mt = 0; mt < 2; ++mt)
            #pragma unroll
            for (int k0 = 0; k0 < 2; ++k0) {
                const int row = qt * TQ + stripe * 32 + mt * 16 + lc;
                const int d0  = k0 * 32 + quad * 8;
                const float4 x = *(const float4*)(Qg + qhead + (size_t)row * D + d0);
                const float4 y = *(const float4*)(Qg + qhead + (size_t)row * D + d0 + 4);
                float f[8] = {x.x, x.y, x.z, x.w, y.x, y.y, y.z, y.w};
                #pragma unroll
                for (int j = 0; j < 8; ++j) {
                    const float v = f[j] * 0.125f;
                    const unsigned short hi = f2bf(v);
                    qfh[mt][k0][j] = (short)hi;
                    qfl[mt][k0][j] = (short)f2bf(v - bf2f(hi));
                }
            }
    }
    f32x4 O_[2][8];
    #pragma unroll
    for (int mt = 0; mt < 2; ++mt)
        #pragma unroll
        for (int nt = 0; nt < 8; ++nt) O_[mt][nt] = (f32x4){0.f, 0.f, 0.f, 0.f};
    float m_[2][4], l_[2][4], a_[2][4];
    #pragma unroll
    for (int mt = 0; mt < 2; ++mt)
        #pragma unroll
        for (int i = 0; i < 4; ++i) { m_[mt][i] = -1e30f; l_[mt][i] = 0.f; }
    const int s_hh = tid >> 7;
    const int s_n  = (tid >> 2) & 31;
    const int s_d0 = (tid & 3) * 16;
    const int s_e0 = tid & 31;
    const int s_s0 = ((tid >> 5) & 7) * 4;
    const int s_sb = s_s0 >> 3;
    const int s_hs = (s_s0 & 4) ? 1 : 0;
    for (int kt = 0; kt < NT / TS; ++kt) {
        const int kb = kt * TS;
        __syncthreads();
        {
            const float* kp = Kg + koff0 + (size_t)s_hh * NT * D +
                              (size_t)(kb + s_n) * D + s_d0;
            const float4 x0 = ((const float4*)kp)[0];
            const float4 x1 = ((const float4*)kp)[1];
            const float4 x2 = ((const float4*)kp)[2];
            const float4 x3 = ((const float4*)kp)[3];
            float f[16] = {x0.x, x0.y, x0.z, x0.w, x1.x, x1.y, x1.z, x1.w,
                           x2.x, x2.y, x2.z, x2.w, x3.x, x3.y, x3.z, x3.w};
            short8 c0h, c0l, c1h, c1l;
            #pragma unroll
            for (int j = 0; j < 8; ++j) {
                unsigned short hi = f2bf(f[j]);
                c0h[j] = (short)hi; c0l[j] = (short)f2bf(f[j] - bf2f(hi));
                hi = f2bf(f[8 + j]);
                c1h[j] = (short)hi; c1l[j] = (short)f2bf(f[8 + j] - bf2f(hi));
            }
            const int db0 = s_d0 >> 3;
            sm.L.kh[s_hh][db0 * 33 + s_n]       = c0h;
            sm.L.kl[s_hh][db0 * 33 + s_n]       = c0l;
            sm.L.kh[s_hh][(db0 + 1) * 33 + s_n] = c1h;
            sm.L.kl[s_hh][(db0 + 1) * 33 + s_n] = c1l;
        }
        {
            #pragma unroll
            for (int j = 0; j < 4; ++j) {
                const int e = s_e0 + 32 * j;
                float f[4];
                #pragma unroll
                for (int i = 0; i < 4; ++i)
                    f[i] = Vg[voff + (size_t)(kb + s_s0 + i) * DV + e];
                short4v hi4, lo4;
                #pragma unroll
                for (int i = 0; i < 4; ++i) {
                    const unsigned short hi = f2bf(f[i]);
                    hi4[i] = (short)hi;
                    lo4[i] = (short)f2bf(f[i] - bf2f(hi));
                }
                ((short4v*)&sm.L.vh[s_sb * 129 + e])[s_hs] = hi4;
                ((short4v*)&sm.L.vl[s_sb * 129 + e])[s_hs] = lo4;
            }
        }
        __syncthreads();
        f32x4 s_f[2][2];
        #pragma unroll
        for (int mt = 0; mt < 2; ++mt)
            #pragma unroll
            for (int nt = 0; nt < 2; ++nt) s_f[mt][nt] = (f32x4){0.f, 0.f, 0.f, 0.f};
        #pragma unroll
        for (int k0 = 0; k0 < 2; ++k0)
            #pragma unroll
            for (int nt = 0; nt < 2; ++nt) {
                const short8 kh = sm.L.kh[hh][(4 * k0 + quad) * 33 + nt * 16 + lc];
                const short8 kl = sm.L.kl[hh][(4 * k0 + quad) * 33 + nt * 16 + lc];
                #pragma unroll
                for (int mt = 0; mt < 2; ++mt) {
                    s_f[mt][nt] = MFMA16(qfh[mt][k0], kh, s_f[mt][nt]);
                    s_f[mt][nt] = MFMA16(qfl[mt][k0], kh, s_f[mt][nt]);
                    s_f[mt][nt] = MFMA16(qfh[mt][k0], kl, s_f[mt][nt]);
                }
            }
        #pragma unroll
        for (int mt = 0; mt < 2; ++mt)
            #pragma unroll
            for (int i = 0; i < 4; ++i) {
                const float v0 = s_f[mt][0][i], v1 = s_f[mt][1][i];
                float mx = fmaxf(v0, v1);
                mx = fmaxf(mx, __shfl_xor(mx, 1));
                mx = fmaxf(mx, __shfl_xor(mx, 2));
                mx = fmaxf(mx, __shfl_xor(mx, 4));
                mx = fmaxf(mx, __shfl_xor(mx, 8));
                const float mn = fmaxf(m_[mt][i], mx);
                const float al = __expf(m_[mt][i] - mn);
                const float p0 = __expf(v0 - mn);
                const float p1 = __expf(v1 - mn);
                float rs = p0 + p1;
                rs += __shfl_xor(rs, 1);
                rs += __shfl_xor(rs, 2);
                rs += __shfl_xor(rs, 4);
                rs += __shfl_xor(rs, 8);
                l_[mt][i] = l_[mt][i] * al + rs;
                m_[mt][i] = mn;
                a_[mt][i] = al;
                const int r = stripe * 32 + mt * 16 + quad * 4 + i;
                const unsigned short h0 = f2bf(p0);
                sm.L.ph[hh][r * 40 + lc]      = h0;
                sm.L.pl[hh][r * 40 + lc]      = f2bf(p0 - bf2f(h0));
                const unsigned short h1 = f2bf(p1);
                sm.L.ph[hh][r * 40 + 16 + lc] = h1;
                sm.L.pl[hh][r * 40 + 16 + lc] = f2bf(p1 - bf2f(h1));
            }
        __syncthreads();
        #pragma unroll
        for (int mt = 0; mt < 2; ++mt)
            #pragma unroll
            for (int nt = 0; nt < 8; ++nt)
                #pragma unroll
                for (int i = 0; i < 4; ++i) O_[mt][nt][i] *= a_[mt][i];
        short8 pah[2], pal[2];
        #pragma unroll
        for (int mt = 0; mt < 2; ++mt) {
            const int r = stripe * 32 + mt * 16 + lc;
            pah[mt] = *(const short8*)&sm.L.ph[hh][r * 40 + quad * 8];
            pal[mt] = *(const short8*)&sm.L.pl[hh][r * 40 + quad * 8];
        }
        #pragma unroll
        for (int nt = 0; nt < 8; ++nt) {
            const short8 vh = sm.L.vh[quad * 129 + nt * 16 + lc];
            const short8 vl = sm.L.vl[quad * 129 + nt * 16 + lc];
            #pragma unroll
            for (int mt = 0; mt < 2; ++mt) {
                O_[mt][nt] = MFMA16(pah[mt], vh, O_[mt][nt]);
                O_[mt][nt] = MFMA16(pal[mt], vh, O_[mt][nt]);
                O_[mt][nt] = MFMA16(pah[mt], vl, O_[mt][nt]);
            }
        }
    }
    __syncthreads();
    if (hh == 1) {
        #pragma unroll
        for (int mt = 0; mt < 2; ++mt)
            #pragma unroll
            for (int i = 0; i < 4; ++i) {
                const float inv = lam / l_[mt][i];
                const int r = mt * 16 + quad * 4 + i;
                #pragma unroll
                for (int nt = 0; nt < 8; ++nt)
                    sm.epi[stripe][r][nt * 16 + lc] = O_[mt][nt][i] * inv;
            }
    }
    __syncthreads();
    if (hh == 0) {
        float wvv[8];
        #pragma unroll
        for (int nt = 0; nt < 8; ++nt) wvv[nt] = Wg[nt * 16 + lc];
        #pragma unroll
        for (int mt = 0; mt < 2; ++mt)
            #pragma unroll
            for (int i = 0; i < 4; ++i) {
                const float inv1 = 1.f / l_[mt][i];
                const int r = mt * 16 + quad * 4 + i;
                float od[8];
                float ss = 0.f;
                #pragma unroll
                for (int nt = 0; nt < 8; ++nt) {
                    od[nt] = O_[mt][nt][i] * inv1 - sm.epi[stripe][r][nt * 16 + lc];
                    ss = fmaf(od[nt], od[nt], ss);
                }
                ss += __shfl_xor(ss, 1);
                ss += __shfl_xor(ss, 2);
                ss += __shfl_xor(ss, 4);
                ss += __shfl_xor(ss, 8);
                const float rsq = rsqrtf(ss * (1.f / 128.f) + 1e-5f) * OUT_SCALE;
                const int rowg = qt * TQ + stripe * 32 + r;
                const size_t base =
                    ((size_t)b * NT + rowg) * (size_t)(8 * DV) + (size_t)h * DV;
                #pragma unroll
                for (int nt = 0; nt < 8; ++nt)
                    Outg[base + nt * 16 + lc] = od[nt] * rsq * wvv[nt];
            }
    }
}

extern "C" void kernel_launch(void* const* d_in, const int* in_sizes, int n_in,
                              void* d_out, int out_size, void* d_ws, size_t ws_size,
                              hipStream_t stream) {
    const float* Q   = (const float*)d_in[0];
    const float* K   = (const float*)d_in[1];
    const float* V   = (const float*)d_in[2];
    const float* lq1 = (const float*)d_in[3];
    const float* lk1 = (const float*)d_in[4];
    const float* lq2 = (const float*)d_in[5];
    const float* lk2 = (const float*)d_in[6];
    const float* W   = (const float*)d_in[7];
    float* Out = (float*)d_out;
    const size_t NEED = 2ull * 4194304ull * sizeof(u16) + 16;   // 16.8 MB
    if (ws_size >= NEED) {
        u16*   Kf   = (u16*)d_ws;
        u16*   Vf   = Kf + 4194304;
        float* lamw = (float*)(Vf + 4194304);
        prep_kv<<<2561, 256, 0, stream>>>(K, V, lq1, lk1, lq2, lk2, Kf, Vf, lamw);
        diffattn_mfma12<<<dim3(NT / TQ, 16), 512, 0, stream>>>(
            Q, Kf, Vf, lamw, W, Out);
    } else {
        diffattn_fb<<<dim3(NT / TQ, 16), 256, 0, stream>>>(
            Q, K, V, lq1, lk1, lq2, lk2, W, Out);
    }
}

// Round 3
// 168.861 us; speedup vs baseline: 1.0984x; 1.0043x over previous
//
#include <hip/hip_runtime.h>
#include <math.h>

// DiffAttn flash R13 — barrier-free main loop. prep_kv now writes Kf AND Vf in
// FRAGMENT-CONTIGUOUS order (per 16x16 MFMA fragment: 64 lanes x 16B = 1KB
// contiguous, lane-order = quad*16+lc), so the flash kernel loads A/B frags
// directly from global as perfectly-coalesced 1KB wave-loads. No LDS staging,
// no __syncthreads in the hot loop -> waves free-run and MFMA/VALU/VMEM pipes
// overlap via natural desync. Kf/Vf (16.8MB) are L3-resident; time-correlated
// hot set ~2MB/XCD fits L2. LDS keeps only the epilogue buffers (34.8KB).
// Byte-identical fragment content vs R12 (verified by construction), so the
// QK/softmax/PV math and epilogue are unchanged.
// B=2, 8 head-pairs, T=S=2048, D=64, DV=128, fp32 in/out.

#define NT    2048
#define D     64
#define DV    128
#define TQ    64
#define TS    32
#define NROUND (NT / (2 * TS))   // 32 rounds, 2 tiles/round (one per ks group)

#define LAMBDA_INIT 0.70082066706704814f   // 0.8 - 0.6*exp(-1.8)
#define OUT_SCALE   0.29917933293295186f   // 1 - LAMBDA_INIT
#define QSCALE      0.18033688011112042f   // 0.125 * log2(e): softmax in exp2 domain

typedef __attribute__((ext_vector_type(8)))  short    short8;
typedef __attribute__((ext_vector_type(4)))  short    short4v;
typedef __attribute__((ext_vector_type(8)))  _Float16 half8;
typedef __attribute__((ext_vector_type(2)))  __fp16   fp16x2;
typedef __attribute__((ext_vector_type(4)))  float    f32x4;
typedef unsigned short u16;
typedef unsigned int   u32;

#define MFMAH(a, b, c)  __builtin_amdgcn_mfma_f32_16x16x32_f16(a, b, c, 0, 0, 0)
#define MFMA16(a, b, c) __builtin_amdgcn_mfma_f32_16x16x32_bf16(a, b, c, 0, 0, 0)

#if __has_builtin(__builtin_amdgcn_exp2f)
#define EXP2F(x) __builtin_amdgcn_exp2f(x)
#else
#define EXP2F(x) exp2f(x)
#endif

union Hu { half8 v; _Float16 e[8]; u16 s[8]; short8 sv; };

__device__ __forceinline__ u16 f2h(float x) {
    Hu u; u.e[0] = (_Float16)x; return u.s[0];
}

// ---------------- prep_kv ----------------------------------------------------
// blocks 0..1023:   K -> fp16 fragment-contiguous Kf.
//   Kf chunk layout: [(bh2*64 + tile)*4 + k0*2 + mt] * 1KB, lane=quad*16+lc
//   holds K[bh2][tile*32 + mt*16 + lc][k0*32 + quad*8 + 0..7].
// block 1024:       lambda scalar.
// blocks 1025..1536: V -> fp16 fragment-contiguous Vf with baked 16x16 kappa
//   permutation (same bytes per fragment as R12's LDS image).
//   Vf chunk layout: [(bh8*64 + tile)*8 + nt] * 1KB, lane=quad*16+lc holds
//   permuted-V slots for e = nt*16+lc, storage chunk c=quad:
//   slot j = V[key tile*32 + kappa(quad,j)][e], kappa(c,j)=4c+(j&3)+16*(j>>2).
__global__ __launch_bounds__(256) void prep_kv(
    const float* __restrict__ Kg, const float* __restrict__ Vg,
    const float* __restrict__ lq1, const float* __restrict__ lk1,
    const float* __restrict__ lq2, const float* __restrict__ lk2,
    u16* __restrict__ Kf, u16* __restrict__ Vf, float* __restrict__ lamw)
{
    __shared__ u16 th[64 * 136];   // V: [e][s] stride 136; K: [key][d] stride 80
    const int bid = blockIdx.x;
    const int t   = threadIdx.x;
    if (bid < 1024) {
        // ---- K path: one (head bh2, 64-key tilepair) per block
        const int bh2 = bid >> 5;
        const int tp  = bid & 31;
        {
            const int key = t >> 2;              // 0..63 local key
            const int d0  = (t & 3) * 16;        // 0/16/32/48
            const float* src =
                Kg + ((size_t)bh2 * NT + (size_t)tp * 64 + key) * D + d0;
            const float4 x0 = ((const float4*)src)[0];
            const float4 x1 = ((const float4*)src)[1];
            const float4 x2 = ((const float4*)src)[2];
            const float4 x3 = ((const float4*)src)[3];
            Hu a, b;
            a.e[0] = (_Float16)x0.x; a.e[1] = (_Float16)x0.y;
            a.e[2] = (_Float16)x0.z; a.e[3] = (_Float16)x0.w;
            a.e[4] = (_Float16)x1.x; a.e[5] = (_Float16)x1.y;
            a.e[6] = (_Float16)x1.z; a.e[7] = (_Float16)x1.w;
            b.e[0] = (_Float16)x2.x; b.e[1] = (_Float16)x2.y;
            b.e[2] = (_Float16)x2.z; b.e[3] = (_Float16)x2.w;
            b.e[4] = (_Float16)x3.x; b.e[5] = (_Float16)x3.y;
            b.e[6] = (_Float16)x3.z; b.e[7] = (_Float16)x3.w;
            *(short8*)(th + key * 80 + d0)     = a.sv;
            *(short8*)(th + key * 80 + d0 + 8) = b.sv;
        }
        __syncthreads();
        #pragma unroll
        for (int q = 0; q < 2; ++q) {
            const int c    = t * 2 + q;          // chunk 0..511
            const int tt   = c >> 8;             // tile within pair
            const int k0   = (c >> 7) & 1;
            const int mt   = (c >> 6) & 1;
            const int lane = c & 63;
            const int qd   = lane >> 4, lcl = lane & 15;
            const short8 o =
                *(const short8*)(th + (tt * 32 + mt * 16 + lcl) * 80 +
                                 k0 * 32 + qd * 8);
            const size_t oc =
                (((size_t)(bh2 * 64 + tp * 2 + tt)) * 4 + k0 * 2 + mt) * 512 +
                lane * 8;
            *(short8*)(Kf + oc) = o;
        }
        return;
    }
    if (bid == 1024) {
        if (t == 0) {
            float t1 = 0.f, t2 = 0.f;
            for (int i = 0; i < D; ++i) {
                t1 = fmaf(lq1[i], lk1[i], t1);
                t2 = fmaf(lq2[i], lk2[i], t2);
            }
            lamw[0] = __expf(t1) - __expf(t2) + LAMBDA_INIT;
        }
        return;
    }
    // ---- V path: one (bh8, e-half eb, 128-key block sb) per block
    const int i  = bid - 1025;
    const int bh = i >> 5;
    const int eb = (i >> 4) & 1;
    const int sb = i & 15;
    const size_t vbase = (size_t)bh * NT * DV + (size_t)sb * 128 * DV + eb * 64;
    {
        const int r0 = t >> 4;
        const int c4 = (t & 15) * 4;
        #pragma unroll
        for (int rr = 0; rr < 8; ++rr) {
            const int row = r0 + rr * 16;
            const float4 x = *(const float4*)(Vg + vbase + (size_t)row * DV + c4);
            th[(c4 + 0) * 136 + row] = f2h(x.x);
            th[(c4 + 1) * 136 + row] = f2h(x.y);
            th[(c4 + 2) * 136 + row] = f2h(x.z);
            th[(c4 + 3) * 136 + row] = f2h(x.w);
        }
    }
    __syncthreads();
    #pragma unroll
    for (int q = 0; q < 4; ++q) {
        const int o    = t * 4 + q;        // chunk 0..1023
        const int gt   = o >> 8;           // tile within sb block (0..3)
        const int ntl  = (o >> 6) & 3;     // nt within eb half
        const int lane = o & 63;
        const int cq   = lane >> 4, lcl = lane & 15;
        const int el   = ntl * 16 + lcl;   // e_local 0..63
        Hu ov;
        #pragma unroll
        for (int j = 0; j < 8; ++j)
            ov.s[j] = th[el * 136 + gt * 32 + 4 * cq + (j & 3) + 16 * (j >> 2)];
        const size_t oc =
            (((size_t)(bh * 64 + sb * 4 + gt)) * 8 + eb * 4 + ntl) * 512 +
            lane * 8;
        *(short8*)(Vf + oc) = ov.sv;
    }
}

// --------------------------------- flash kernel ------------------------------
struct SmemE {
    float epi[2][32][132];         // 33792 B
    float lbuf[2][2][2][32];       //  1024 B  [hh][ks][stripe][row]
};

__global__ __launch_bounds__(512, 4) void diffattn_mfma13(
    const float* __restrict__ Qg,
    const u16* __restrict__ Kf, const u16* __restrict__ Vf,
    const float* __restrict__ lamw,
    const float* __restrict__ Wg, float* __restrict__ Outg)
{
    __shared__ SmemE sm;

    const int tid    = threadIdx.x;
    const int wv     = tid >> 6;
    const int lane   = tid & 63;
    const int quad   = lane >> 4;
    const int lc     = lane & 15;
    const int stripe = wv & 1;          // 32-row half of the 64-row q-tile
    const int hh     = (wv >> 1) & 1;   // half-head (softmax 1 vs 2)
    const int ks     = wv >> 2;         // key-split group: tiles 2r+ks
    const int qt     = blockIdx.x;
    const int bh     = blockIdx.y;
    const int b      = bh >> 3, h = bh & 7;

    const int head2b = b * 16 + 2 * h;
    const int bh8    = b * 8 + h;
    const int bh2    = head2b + hh;
    const float lam  = lamw[0];

    // Q B-frags (B[k=d][n=qrow]: n=lc, k=quad*8+j within k0*32), pre-scaled by
    // 0.125*log2e so softmax is a bare v_exp_f32 in exp2 domain.
    half8 qf[2][2];
    {
        const size_t qhead = (size_t)bh2 * NT * D;
        #pragma unroll
        for (int nq = 0; nq < 2; ++nq) {
            const int row = qt * TQ + stripe * 32 + nq * 16 + lc;
            #pragma unroll
            for (int k0 = 0; k0 < 2; ++k0) {
                const int d0 = k0 * 32 + quad * 8;
                const float4 x = *(const float4*)(Qg + qhead + (size_t)row * D + d0);
                const float4 y = *(const float4*)(Qg + qhead + (size_t)row * D + d0 + 4);
                Hu q;
                q.e[0] = (_Float16)(x.x * QSCALE); q.e[1] = (_Float16)(x.y * QSCALE);
                q.e[2] = (_Float16)(x.z * QSCALE); q.e[3] = (_Float16)(x.w * QSCALE);
                q.e[4] = (_Float16)(y.x * QSCALE); q.e[5] = (_Float16)(y.y * QSCALE);
                q.e[6] = (_Float16)(y.z * QSCALE); q.e[7] = (_Float16)(y.w * QSCALE);
                qf[nq][k0] = q.v;
            }
        }
    }

    f32x4 O_[2][8];   // [nq][nt]: row = nq*16+quad*4+i, e = nt*16+lc
    #pragma unroll
    for (int nq = 0; nq < 2; ++nq)
        #pragma unroll
        for (int nt = 0; nt < 8; ++nt) O_[nq][nt] = (f32x4){0.f, 0.f, 0.f, 0.f};
    float lac[2] = {0.f, 0.f};

    // fragment-contiguous global bases (u16 units), + tile*stride per round
    const u32 kbase = (u32)(bh2 * 64) * 2048 + (u32)(lane * 8);
    const u32 vbase = (u32)(bh8 * 64) * 4096 + (u32)(lane * 8);

    const fp16x2 ones = {(__fp16)1.f, (__fp16)1.f};
    const f32x4  z4   = {0.f, 0.f, 0.f, 0.f};

    for (int r = 0; r < NROUND; ++r) {
        const u32 t_ = (u32)(2 * r + ks);
        const u16* kp = Kf + kbase + t_ * 2048;
        const u16* vp = Vf + vbase + t_ * 4096;

        // ---- K frags: 4 coalesced 1KB wave-loads
        half8 kfr[2][2];
        #pragma unroll
        for (int k0 = 0; k0 < 2; ++k0)
            #pragma unroll
            for (int mt = 0; mt < 2; ++mt)
                kfr[k0][mt] = *(const half8*)(kp + (k0 * 2 + mt) * 512);

        // ---- S^T = K·Q^T: key = mt*16 + quad*4 + i, qrow = nq*16 + lc
        f32x4 sf[2][2];
        #pragma unroll
        for (int mt = 0; mt < 2; ++mt)
            #pragma unroll
            for (int nq = 0; nq < 2; ++nq)
                sf[mt][nq] = MFMAH(kfr[0][mt], qf[nq][0], z4);
        #pragma unroll
        for (int mt = 0; mt < 2; ++mt)
            #pragma unroll
            for (int nq = 0; nq < 2; ++nq)
                sf[mt][nq] = MFMAH(kfr[1][mt], qf[nq][1], sf[mt][nq]);

        // ---- fixed-max softmax (exp2 domain) + packed repack to permuted-k
        // A-frag: slot j = mt*4+i holds key 16*(j>>2) + 4*quad + (j&3).
        half8 a8[2];
        #pragma unroll
        for (int nq = 0; nq < 2; ++nq) {
            union { half8 v; fp16x2 h[4]; } a;
            float ls = lac[nq];
            #pragma unroll
            for (int mt = 0; mt < 2; ++mt)
                #pragma unroll
                for (int ip = 0; ip < 2; ++ip) {
                    const float p0 = EXP2F(sf[mt][nq][2 * ip]);
                    const float p1 = EXP2F(sf[mt][nq][2 * ip + 1]);
                    const fp16x2 h2 = __builtin_amdgcn_cvt_pkrtz(p0, p1);
                    a.h[mt * 2 + ip] = h2;
                    ls = __builtin_amdgcn_fdot2(h2, ones, ls, false);
                }
            lac[nq] = ls;
            a8[nq] = a.v;
        }

        // ---- PV: fragment-contiguous V B-frags, two batches of 4 loads
        #pragma unroll
        for (int g = 0; g < 2; ++g) {
            half8 vfr[4];
            #pragma unroll
            for (int n = 0; n < 4; ++n)
                vfr[n] = *(const half8*)(vp + (g * 4 + n) * 512);
            #pragma unroll
            for (int n = 0; n < 4; ++n)
                #pragma unroll
                for (int nq = 0; nq < 2; ++nq)
                    O_[nq][g * 4 + n] = MFMAH(a8[nq], vfr[n], O_[nq][g * 4 + n]);
        }
    }

    // ---- epilogue: merge ks partials ------------------------------------
    // l partials: reduce across quads, publish per (hh,ks,stripe,row)
    {
        float s0 = lac[0], s1 = lac[1];
        s0 += __shfl_xor(s0, 16); s0 += __shfl_xor(s0, 32);
        s1 += __shfl_xor(s1, 16); s1 += __shfl_xor(s1, 32);
        if (quad == 0) {
            sm.lbuf[hh][ks][stripe][lc]      = s0;
            sm.lbuf[hh][ks][stripe][16 + lc] = s1;
        }
    }
    __syncthreads();
    // per-row coefficient from merged l (sign/lam folded for hh1)
    float coef[2][4];
    #pragma unroll
    for (int nq = 0; nq < 2; ++nq)
        #pragma unroll
        for (int i = 0; i < 4; ++i) {
            const int row = nq * 16 + quad * 4 + i;
            const float lt = sm.lbuf[hh][0][stripe][row] +
                             sm.lbuf[hh][1][stripe][row];
            coef[nq][i] = (hh == 0) ? (1.f / lt) : (-lam / lt);
        }
    __syncthreads();
    // 4-phase accumulation of scaled partials into epi
    const int pid = hh * 2 + ks;
    #pragma unroll
    for (int p = 0; p < 4; ++p) {
        if (pid == p) {
            #pragma unroll
            for (int nq = 0; nq < 2; ++nq)
                #pragma unroll
                for (int i = 0; i < 4; ++i) {
                    const int row = nq * 16 + quad * 4 + i;
                    #pragma unroll
                    for (int nt = 0; nt < 8; ++nt) {
                        const int col = nt * 16 + lc;
                        const float v = O_[nq][nt][i] * coef[nq][i];
                        if (p == 0) sm.epi[stripe][row][col] = v;
                        else        sm.epi[stripe][row][col] += v;
                    }
                }
        }
        __syncthreads();
    }
    // RMS + store: wave wv handles rows wv*8 .. wv*8+7 (8 lanes per row)
    {
        const int r0 = wv * 8 + (lane >> 3);
        const int st = r0 >> 5, ri = r0 & 31;
        const int e0 = (lane & 7) * 16;
        float x[16];
        float ssq = 0.f;
        #pragma unroll
        for (int m = 0; m < 16; m += 4) {
            const float4 t4 = *(const float4*)&sm.epi[st][ri][e0 + m];
            x[m] = t4.x; x[m + 1] = t4.y; x[m + 2] = t4.z; x[m + 3] = t4.w;
            ssq += t4.x * t4.x + t4.y * t4.y + t4.z * t4.z + t4.w * t4.w;
        }
        ssq += __shfl_xor(ssq, 1);
        ssq += __shfl_xor(ssq, 2);
        ssq += __shfl_xor(ssq, 4);
        const float rsq = rsqrtf(ssq * (1.f / 128.f) + 1e-5f) * OUT_SCALE;
        const int rowg = qt * TQ + r0;
        const size_t base =
            ((size_t)b * NT + rowg) * (size_t)(8 * DV) + (size_t)h * DV;
        #pragma unroll
        for (int m = 0; m < 16; m += 4) {
            const float4 w4 = *(const float4*)(Wg + e0 + m);
            float4 o4;
            o4.x = x[m] * rsq * w4.x;
            o4.y = x[m + 1] * rsq * w4.y;
            o4.z = x[m + 2] * rsq * w4.z;
            o4.w = x[m + 3] * rsq * w4.w;
            *(float4*)(Outg + base + e0 + m) = o4;
        }
    }
}

// ------------------------ fallback (in-kernel conversion, bf16 split) --------
__device__ __forceinline__ unsigned short f2bf(float x) {
    unsigned u = __float_as_uint(x);
    return (unsigned short)((u + 0x7fffu + ((u >> 16) & 1u)) >> 16);
}
__device__ __forceinline__ float bf2f(unsigned short h) {
    return __uint_as_float(((unsigned)h) << 16);
}

struct SmemB {
    union {
        struct {
            short8 kh[2][264];
            short8 kl[2][264];
            short8 vh[516];
            short8 vl[516];
            unsigned short ph[2][2560];
            unsigned short pl[2][2560];
        } L;
        float epi[2][32][132];
    };
};

__global__ __launch_bounds__(256, 2) void diffattn_fb(
    const float* __restrict__ Qg, const float* __restrict__ Kg,
    const float* __restrict__ Vg,
    const float* __restrict__ lq1, const float* __restrict__ lk1,
    const float* __restrict__ lq2, const float* __restrict__ lk2,
    const float* __restrict__ Wg, float* __restrict__ Outg)
{
    __shared__ SmemB sm;
    const int tid = threadIdx.x;
    const int wv = tid >> 6, lane = tid & 63;
    const int quad = lane >> 4, lc = lane & 15;
    const int stripe = wv & 1, hh = wv >> 1;
    const int qt = blockIdx.x, bh = blockIdx.y;
    const int b = bh >> 3, h = bh & 7;
    const size_t koff0 = ((size_t)(b * 16 + 2 * h)) * NT * D;
    const size_t voff  = ((size_t)(b * 8 + h)) * NT * DV;
    float t1 = 0.f, t2 = 0.f;
    for (int i = 0; i < D; ++i) {
        t1 = fmaf(lq1[i], lk1[i], t1);
        t2 = fmaf(lq2[i], lk2[i], t2);
    }
    const float lam = __expf(t1) - __expf(t2) + LAMBDA_INIT;
    short8 qfh[2][2], qfl[2][2];
    {
        const size_t qhead = ((size_t)(b * 16 + 2 * h + hh)) * NT * D;
        #pragma unroll
        for (int mt = 0; mt < 2; ++mt)
            #pragma unroll
            for (int k0 = 0; k0 < 2; ++k0) {
                const int row = qt * TQ + stripe * 32 + mt * 16 + lc;
                const int d0  = k0 * 32 + quad * 8;
                const float4 x = *(const float4*)(Qg + qhead + (size_t)row * D + d0);
                const float4 y = *(const float4*)(Qg + qhead + (size_t)row * D + d0 + 4);
                float f[8] = {x.x, x.y, x.z, x.w, y.x, y.y, y.z, y.w};
                #pragma unroll
                for (int j = 0; j < 8; ++j) {
                    const float v = f[j] * 0.125f;
                    const unsigned short hi = f2bf(v);
                    qfh[mt][k0][j] = (short)hi;
                    qfl[mt][k0][j] = (short)f2bf(v - bf2f(hi));
                }
            }
    }
    f32x4 O_[2][8];
    #pragma unroll
    for (int mt = 0; mt < 2; ++mt)
        #pragma unroll
        for (int nt = 0; nt < 8; ++nt) O_[mt][nt] = (f32x4){0.f, 0.f, 0.f, 0.f};
    float m_[2][4], l_[2][4], a_[2][4];
    #pragma unroll
    for (int mt = 0; mt < 2; ++mt)
        #pragma unroll
        for (int i = 0; i < 4; ++i) { m_[mt][i] = -1e30f; l_[mt][i] = 0.f; }
    const int s_hh = tid >> 7;
    const int s_n  = (tid >> 2) & 31;
    const int s_d0 = (tid & 3) * 16;
    const int s_e0 = tid & 31;
    const int s_s0 = ((tid >> 5) & 7) * 4;
    const int s_sb = s_s0 >> 3;
    const int s_hs = (s_s0 & 4) ? 1 : 0;
    for (int kt = 0; kt < NT / TS; ++kt) {
        const int kb = kt * TS;
        __syncthreads();
        {
            const float* kp = Kg + koff0 + (size_t)s_hh * NT * D +
                              (size_t)(kb + s_n) * D + s_d0;
            const float4 x0 = ((const float4*)kp)[0];
            const float4 x1 = ((const float4*)kp)[1];
            const float4 x2 = ((const float4*)kp)[2];
            const float4 x3 = ((const float4*)kp)[3];
            float f[16] = {x0.x, x0.y, x0.z, x0.w, x1.x, x1.y, x1.z, x1.w,
                           x2.x, x2.y, x2.z, x2.w, x3.x, x3.y, x3.z, x3.w};
            short8 c0h, c0l, c1h, c1l;
            #pragma unroll
            for (int j = 0; j < 8; ++j) {
                unsigned short hi = f2bf(f[j]);
                c0h[j] = (short)hi; c0l[j] = (short)f2bf(f[j] - bf2f(hi));
                hi = f2bf(f[8 + j]);
                c1h[j] = (short)hi; c1l[j] = (short)f2bf(f[8 + j] - bf2f(hi));
            }
            const int db0 = s_d0 >> 3;
            sm.L.kh[s_hh][db0 * 33 + s_n]       = c0h;
            sm.L.kl[s_hh][db0 * 33 + s_n]       = c0l;
            sm.L.kh[s_hh][(db0 + 1) * 33 + s_n] = c1h;
            sm.L.kl[s_hh][(db0 + 1) * 33 + s_n] = c1l;
        }
        {
            #pragma unroll
            for (int j = 0; j < 4; ++j) {
                const int e = s_e0 + 32 * j;
                float f[4];
                #pragma unroll
                for (int i = 0; i < 4; ++i)
                    f[i] = Vg[voff + (size_t)(kb + s_s0 + i) * DV + e];
                short4v hi4, lo4;
                #pragma unroll
                for (int i = 0; i < 4; ++i) {
                    const unsigned short hi = f2bf(f[i]);
                    hi4[i] = (short)hi;
                    lo4[i] = (short)f2bf(f[i] - bf2f(hi));
                }
                ((short4v*)&sm.L.vh[s_sb * 129 + e])[s_hs] = hi4;
                ((short4v*)&sm.L.vl[s_sb * 129 + e])[s_hs] = lo4;
            }
        }
        __syncthreads();
        f32x4 s_f[2][2];
        #pragma unroll
        for (int mt = 0; mt < 2; ++mt)
            #pragma unroll
            for (int nt = 0; nt < 2; ++nt) s_f[mt][nt] = (f32x4){0.f, 0.f, 0.f, 0.f};
        #pragma unroll
        for (int k0 = 0; k0 < 2; ++k0)
            #pragma unroll
            for (int nt = 0; nt < 2; ++nt) {
                const short8 kh = sm.L.kh[hh][(4 * k0 + quad) * 33 + nt * 16 + lc];
                const short8 kl = sm.L.kl[hh][(4 * k0 + quad) * 33 + nt * 16 + lc];
                #pragma unroll
                for (int mt = 0; mt < 2; ++mt) {
                    s_f[mt][nt] = MFMA16(qfh[mt][k0], kh, s_f[mt][nt]);
                    s_f[mt][nt] = MFMA16(qfl[mt][k0], kh, s_f[mt][nt]);
                    s_f[mt][nt] = MFMA16(qfh[mt][k0], kl, s_f[mt][nt]);
                }
            }
        #pragma unroll
        for (int mt = 0; mt < 2; ++mt)
            #pragma unroll
            for (int i = 0; i < 4; ++i) {
                const float v0 = s_f[mt][0][i], v1 = s_f[mt][1][i];
                float mx = fmaxf(v0, v1);
                mx = fmaxf(mx, __shfl_xor(mx, 1));
                mx = fmaxf(mx, __shfl_xor(mx, 2));
                mx = fmaxf(mx, __shfl_xor(mx, 4));
                mx = fmaxf(mx, __shfl_xor(mx, 8));
                const float mn = fmaxf(m_[mt][i], mx);
                const float al = __expf(m_[mt][i] - mn);
                const float p0 = __expf(v0 - mn);
                const float p1 = __expf(v1 - mn);
                float rs = p0 + p1;
                rs += __shfl_xor(rs, 1);
                rs += __shfl_xor(rs, 2);
                rs += __shfl_xor(rs, 4);
                rs += __shfl_xor(rs, 8);
                l_[mt][i] = l_[mt][i] * al + rs;
                m_[mt][i] = mn;
                a_[mt][i] = al;
                const int r = stripe * 32 + mt * 16 + quad * 4 + i;
                const unsigned short h0 = f2bf(p0);
                sm.L.ph[hh][r * 40 + lc]      = h0;
                sm.L.pl[hh][r * 40 + lc]      = f2bf(p0 - bf2f(h0));
                const unsigned short h1 = f2bf(p1);
                sm.L.ph[hh][r * 40 + 16 + lc] = h1;
                sm.L.pl[hh][r * 40 + 16 + lc] = f2bf(p1 - bf2f(h1));
            }
        __syncthreads();
        #pragma unroll
        for (int mt = 0; mt < 2; ++mt)
            #pragma unroll
            for (int nt = 0; nt < 8; ++nt)
                #pragma unroll
                for (int i = 0; i < 4; ++i) O_[mt][nt][i] *= a_[mt][i];
        short8 pah[2], pal[2];
        #pragma unroll
        for (int mt = 0; mt < 2; ++mt) {
            const int r = stripe * 32 + mt * 16 + lc;
            pah[mt] = *(const short8*)&sm.L.ph[hh][r * 40 + quad * 8];
            pal[mt] = *(const short8*)&sm.L.pl[hh][r * 40 + quad * 8];
        }
        #pragma unroll
        for (int nt = 0; nt < 8; ++nt) {
            const short8 vh = sm.L.vh[quad * 129 + nt * 16 + lc];
            const short8 vl = sm.L.vl[quad * 129 + nt * 16 + lc];
            #pragma unroll
            for (int mt = 0; mt < 2; ++mt) {
                O_[mt][nt] = MFMA16(pah[mt], vh, O_[mt][nt]);
                O_[mt][nt] = MFMA16(pal[mt], vh, O_[mt][nt]);
                O_[mt][nt] = MFMA16(pah[mt], vl, O_[mt][nt]);
            }
        }
    }
    __syncthreads();
    if (hh == 1) {
        #pragma unroll
        for (int mt = 0; mt < 2; ++mt)
            #pragma unroll
            for (int i = 0; i < 4; ++i) {
                const float inv = lam / l_[mt][i];
                const int r = mt * 16 + quad * 4 + i;
                #pragma unroll
                for (int nt = 0; nt < 8; ++nt)
                    sm.epi[stripe][r][nt * 16 + lc] = O_[mt][nt][i] * inv;
            }
    }
    __syncthreads();
    if (hh == 0) {
        float wvv[8];
        #pragma unroll
        for (int nt = 0; nt < 8; ++nt) wvv[nt] = Wg[nt * 16 + lc];
        #pragma unroll
        for (int mt = 0; mt < 2; ++mt)
            #pragma unroll
            for (int i = 0; i < 4; ++i) {
                const float inv1 = 1.f / l_[mt][i];
                const int r = mt * 16 + quad * 4 + i;
                float od[8];
                float ss = 0.f;
                #pragma unroll
                for (int nt = 0; nt < 8; ++nt) {
                    od[nt] = O_[mt][nt][i] * inv1 - sm.epi[stripe][r][nt * 16 + lc];
                    ss = fmaf(od[nt], od[nt], ss);
                }
                ss += __shfl_xor(ss, 1);
                ss += __shfl_xor(ss, 2);
                ss += __shfl_xor(ss, 4);
                ss += __shfl_xor(ss, 8);
                const float rsq = rsqrtf(ss * (1.f / 128.f) + 1e-5f) * OUT_SCALE;
                const int rowg = qt * TQ + stripe * 32 + r;
                const size_t base =
                    ((size_t)b * NT + rowg) * (size_t)(8 * DV) + (size_t)h * DV;
                #pragma unroll
                for (int nt = 0; nt < 8; ++nt)
                    Outg[base + nt * 16 + lc] = od[nt] * rsq * wvv[nt];
            }
    }
}

extern "C" void kernel_launch(void* const* d_in, const int* in_sizes, int n_in,
                              void* d_out, int out_size, void* d_ws, size_t ws_size,
                              hipStream_t stream) {
    const float* Q   = (const float*)d_in[0];
    const float* K   = (const float*)d_in[1];
    const float* V   = (const float*)d_in[2];
    const float* lq1 = (const float*)d_in[3];
    const float* lk1 = (const float*)d_in[4];
    const float* lq2 = (const float*)d_in[5];
    const float* lk2 = (const float*)d_in[6];
    const float* W   = (const float*)d_in[7];
    float* Out = (float*)d_out;
    const size_t NEED = 2ull * 4194304ull * sizeof(u16) + 16;   // 16.8 MB
    if (ws_size >= NEED) {
        u16*   Kf   = (u16*)d_ws;
        u16*   Vf   = Kf + 4194304;
        float* lamw = (float*)(Vf + 4194304);
        prep_kv<<<1537, 256, 0, stream>>>(K, V, lq1, lk1, lq2, lk2, Kf, Vf, lamw);
        diffattn_mfma13<<<dim3(NT / TQ, 16), 512, 0, stream>>>(
            Q, Kf, Vf, lamw, W, Out);
    } else {
        diffattn_fb<<<dim3(NT / TQ, 16), 256, 0, stream>>>(
            Q, K, V, lq1, lk1, lq2, lk2, W, Out);
    }
}